// Round 1
// baseline (185.611 us; speedup 1.0000x reference)
//
#include <hip/hip_runtime.h>
#include <math.h>

#define WIN 11
#define OH 32
#define OW 64
#define IH (OH + WIN - 1)   // 42
#define IW (OW + WIN - 1)   // 74
#define VSTR 77             // odd stride -> conflict-free phase-C reads
#define IMG 512
#define OUTD 502            // 512 - 10 (VALID)
#define NIMG 64

struct GW { float w[WIN]; };

__global__ __launch_bounds__(256) void ssim_zero(double* acc) {
    acc[0] = 0.0;
}

__global__ __launch_bounds__(256) void ssim_kernel(
    const float* __restrict__ X, const float* __restrict__ Y,
    double* __restrict__ acc, GW gw)
{
    __shared__ float sX[IH * IW];
    __shared__ float sY[IH * IW];
    __shared__ float vb[5][OH * VSTR];
    __shared__ float red[4];

    const int tid = threadIdx.x;
    const int tC = blockIdx.x, tR = blockIdx.y, b = blockIdx.z;
    const int gr0 = tR * OH, gc0 = tC * OW;
    const float* Xb = X + (size_t)b * (IMG * IMG);
    const float* Yb = Y + (size_t)b * (IMG * IMG);

    // ---- Phase A: stage raw tiles (clamped at image edge; clamped values
    // only ever feed outputs that are masked out of the reduction) ----
    for (int i = tid; i < IH * IW; i += 256) {
        int rr = i / IW, cc = i - rr * IW;
        int gr = gr0 + rr; if (gr > IMG - 1) gr = IMG - 1;
        int gc = gc0 + cc; if (gc > IMG - 1) gc = IMG - 1;
        sX[i] = Xb[gr * IMG + gc];
        sY[i] = Yb[gr * IMG + gc];
    }
    __syncthreads();

    // ---- Phase B: vertical 11-tap conv of 5 channels, 4 stacked rows/task ----
    for (int j = tid; j < (OH / 4) * IW; j += 256) {
        int g = j / IW;
        int c = j - g * IW;
        int r0 = g * 4;
        float aX[4]  = {0, 0, 0, 0}, aY[4]  = {0, 0, 0, 0};
        float aXX[4] = {0, 0, 0, 0}, aYY[4] = {0, 0, 0, 0};
        float aXY[4] = {0, 0, 0, 0};
        #pragma unroll
        for (int k = 0; k < 4 + WIN - 1; ++k) {
            float xv = sX[(r0 + k) * IW + c];
            float yv = sY[(r0 + k) * IW + c];
            float xx = xv * xv, yy = yv * yv, xy = xv * yv;
            #pragma unroll
            for (int i2 = 0; i2 < 4; ++i2) {
                int t = k - i2;
                if (t >= 0 && t < WIN) {        // compile-time after unroll
                    float wt = gw.w[t];
                    aX[i2]  += wt * xv;  aY[i2]  += wt * yv;
                    aXX[i2] += wt * xx;  aYY[i2] += wt * yy;
                    aXY[i2] += wt * xy;
                }
            }
        }
        #pragma unroll
        for (int i2 = 0; i2 < 4; ++i2) {
            vb[0][(r0 + i2) * VSTR + c] = aX[i2];
            vb[1][(r0 + i2) * VSTR + c] = aY[i2];
            vb[2][(r0 + i2) * VSTR + c] = aXX[i2];
            vb[3][(r0 + i2) * VSTR + c] = aYY[i2];
            vb[4][(r0 + i2) * VSTR + c] = aXY[i2];
        }
    }
    __syncthreads();

    // ---- Phase C: horizontal 11-tap conv + SSIM, 8 outputs/thread ----
    const int r  = tid >> 3;
    const int c0 = (tid & 7) * 8;

    float m1[8], m2[8], xx8[8], yy8[8], xy8[8];
    auto hconv = [&](const float* src, float* out8) {
        float w18[8 + WIN - 1];
        #pragma unroll
        for (int j = 0; j < 8 + WIN - 1; ++j) w18[j] = src[c0 + j];
        #pragma unroll
        for (int o = 0; o < 8; ++o) {
            float s = 0.f;
            #pragma unroll
            for (int t = 0; t < WIN; ++t) s += gw.w[t] * w18[o + t];
            out8[o] = s;
        }
    };
    hconv(&vb[0][r * VSTR], m1);
    hconv(&vb[1][r * VSTR], m2);
    hconv(&vb[2][r * VSTR], xx8);
    hconv(&vb[3][r * VSTR], yy8);
    hconv(&vb[4][r * VSTR], xy8);

    const float C1 = 1e-4f, C2 = 9e-4f;
    float lsum = 0.f;
    const int ogr = gr0 + r;
    #pragma unroll
    for (int o = 0; o < 8; ++o) {
        int ogc = gc0 + c0 + o;
        float mu1 = m1[o], mu2 = m2[o];
        float mu1s = mu1 * mu1, mu2s = mu2 * mu2, m12 = mu1 * mu2;
        float s1  = xx8[o] - mu1s;
        float s2  = yy8[o] - mu2s;
        float s12 = xy8[o] - m12;
        float cs = (2.f * s12 + C2) / (s1 + s2 + C2);
        float ss = ((2.f * m12 + C1) / (mu1s + mu2s + C1)) * cs;
        if (ogr < OUTD && ogc < OUTD) lsum += ss;
    }

    // ---- block reduce -> one double atomic per block ----
    #pragma unroll
    for (int off = 32; off > 0; off >>= 1)
        lsum += __shfl_down(lsum, off, 64);
    if ((tid & 63) == 0) red[tid >> 6] = lsum;
    __syncthreads();
    if (tid == 0) {
        float bs = red[0] + red[1] + red[2] + red[3];
        atomicAdd(acc, (double)bs);
    }
}

__global__ void ssim_finalize(const double* __restrict__ acc,
                              float* __restrict__ out) {
    out[0] = 1.0f - (float)(acc[0] / (double)((long long)NIMG * OUTD * OUTD));
}

extern "C" void kernel_launch(void* const* d_in, const int* in_sizes, int n_in,
                              void* d_out, int out_size, void* d_ws, size_t ws_size,
                              hipStream_t stream) {
    const float* X = (const float*)d_in[0];
    const float* Y = (const float*)d_in[1];
    double* acc = (double*)d_ws;
    float* out = (float*)d_out;

    // Exact pytorch_msssim Gaussian window, computed in double on host.
    GW gw;
    double c[WIN], s = 0.0;
    for (int i = 0; i < WIN; ++i) {
        double d = (double)i - (double)(WIN / 2);
        c[i] = exp(-(d * d) / (2.0 * 1.5 * 1.5));
        s += c[i];
    }
    for (int i = 0; i < WIN; ++i) gw.w[i] = (float)(c[i] / s);

    ssim_zero<<<1, 1, 0, stream>>>(acc);
    dim3 grid(IMG / OW, IMG / OH, NIMG);   // (8, 16, 64)
    ssim_kernel<<<grid, 256, 0, stream>>>(X, Y, acc, gw);
    ssim_finalize<<<1, 1, 0, stream>>>(acc, out);
}

// Round 2
// 121.702 us; speedup vs baseline: 1.5251x; 1.5251x over previous
//
#include <hip/hip_runtime.h>
#include <math.h>

#define WIN 11
#define OH 32
#define OW 64
#define IW 74               // vb columns actually used (0..73)
#define VSTR 84             // vb row stride in floats: 16B-aligned, bank-spreading
#define PLANE (OH * VSTR)   // 2688 floats per channel
#define IMG 512
#define OUTD 502            // 512 - 10 (VALID)
#define NIMG 64

struct GW { float w[WIN]; };

__global__ __launch_bounds__(64) void ssim_zero(double* acc) {
    acc[0] = 0.0;
}

__global__ __launch_bounds__(256) void ssim_kernel(
    const float* __restrict__ X, const float* __restrict__ Y,
    double* __restrict__ acc, GW gw)
{
    __shared__ float vb[5 * PLANE];
    __shared__ float red[4];

    const int tid = threadIdx.x;
    const int tC = blockIdx.x, tR = blockIdx.y, b = blockIdx.z;
    const int gr0 = tR * OH, gc0 = tC * OW;
    const float* __restrict__ Xb = X + (size_t)b * (IMG * IMG);
    const float* __restrict__ Yb = Y + (size_t)b * (IMG * IMG);

    // ---- Phase B: vertical 11-tap conv of 5 derived channels, straight from
    // global (coalesced float4; L1/L2 serve the ~3.5x halo re-reads).
    // Task = 4 output rows x 4 cols. 8 row-groups x 19 col-groups = 152 tasks.
    if (tid < 152) {
        const int rg = tid / 19, cg = tid - rg * 19;
        const int r0 = rg * 4;
        int gc = gc0 + cg * 4;
        if (gc > IMG - 4) gc = IMG - 4;   // only cols that feed masked outputs

        float a[5][4][4] = {};
        #pragma unroll
        for (int k = 0; k < 4 + WIN - 1; ++k) {
            int gr = gr0 + r0 + k; if (gr > IMG - 1) gr = IMG - 1;
            const float4 xv = *reinterpret_cast<const float4*>(Xb + (size_t)gr * IMG + gc);
            const float4 yv = *reinterpret_cast<const float4*>(Yb + (size_t)gr * IMG + gc);
            float xs[4] = {xv.x, xv.y, xv.z, xv.w};
            float ys[4] = {yv.x, yv.y, yv.z, yv.w};
            float xx[4], yy[4], xy[4];
            #pragma unroll
            for (int c = 0; c < 4; ++c) {
                xx[c] = xs[c] * xs[c];
                yy[c] = ys[c] * ys[c];
                xy[c] = xs[c] * ys[c];
            }
            #pragma unroll
            for (int i2 = 0; i2 < 4; ++i2) {
                const int t = k - i2;
                if (t >= 0 && t < WIN) {     // compile-time after unroll
                    const float wt = gw.w[t];
                    #pragma unroll
                    for (int c = 0; c < 4; ++c) {
                        a[0][i2][c] += wt * xs[c];
                        a[1][i2][c] += wt * ys[c];
                        a[2][i2][c] += wt * xx[c];
                        a[3][i2][c] += wt * yy[c];
                        a[4][i2][c] += wt * xy[c];
                    }
                }
            }
        }
        #pragma unroll
        for (int ch = 0; ch < 5; ++ch) {
            #pragma unroll
            for (int i2 = 0; i2 < 4; ++i2) {
                float4 v = make_float4(a[ch][i2][0], a[ch][i2][1],
                                       a[ch][i2][2], a[ch][i2][3]);
                *reinterpret_cast<float4*>(&vb[ch * PLANE + (r0 + i2) * VSTR + cg * 4]) = v;
            }
        }
    }
    __syncthreads();

    // ---- Phase C: horizontal 11-tap conv + SSIM, 8 outputs/thread ----
    const int r  = tid >> 3;
    const int c0 = (tid & 7) * 8;
    const float* vrow = &vb[r * VSTR + c0];

    float m[5][8];
    #pragma unroll
    for (int ch = 0; ch < 5; ++ch) {
        const float* p = vrow + ch * PLANE;
        float w18[18];
        *reinterpret_cast<float4*>(&w18[0])  = *reinterpret_cast<const float4*>(p);
        *reinterpret_cast<float4*>(&w18[4])  = *reinterpret_cast<const float4*>(p + 4);
        *reinterpret_cast<float4*>(&w18[8])  = *reinterpret_cast<const float4*>(p + 8);
        *reinterpret_cast<float4*>(&w18[12]) = *reinterpret_cast<const float4*>(p + 12);
        *reinterpret_cast<float2*>(&w18[16]) = *reinterpret_cast<const float2*>(p + 16);
        #pragma unroll
        for (int o = 0; o < 8; ++o) {
            float s = 0.f;
            #pragma unroll
            for (int t = 0; t < WIN; ++t) s += gw.w[t] * w18[o + t];
            m[ch][o] = s;
        }
    }

    const float C1 = 1e-4f, C2 = 9e-4f;
    float lsum = 0.f;
    const int ogr = gr0 + r;
    #pragma unroll
    for (int o = 0; o < 8; ++o) {
        const int ogc = gc0 + c0 + o;
        float mu1 = m[0][o], mu2 = m[1][o];
        float mu1s = mu1 * mu1, mu2s = mu2 * mu2, m12 = mu1 * mu2;
        float s1  = m[2][o] - mu1s;
        float s2  = m[3][o] - mu2s;
        float s12 = m[4][o] - m12;
        float num = (2.f * s12 + C2) * (2.f * m12 + C1);
        float den = (s1 + s2 + C2) * (mu1s + mu2s + C1);
        float ss  = num * __builtin_amdgcn_rcpf(den);
        if (ogr < OUTD && ogc < OUTD) lsum += ss;
    }

    // ---- block reduce -> one double atomic per block ----
    #pragma unroll
    for (int off = 32; off > 0; off >>= 1)
        lsum += __shfl_down(lsum, off, 64);
    if ((tid & 63) == 0) red[tid >> 6] = lsum;
    __syncthreads();
    if (tid == 0) {
        float bs = red[0] + red[1] + red[2] + red[3];
        atomicAdd(acc, (double)bs);
    }
}

__global__ void ssim_finalize(const double* __restrict__ acc,
                              float* __restrict__ out) {
    out[0] = 1.0f - (float)(acc[0] / (double)((long long)NIMG * OUTD * OUTD));
}

extern "C" void kernel_launch(void* const* d_in, const int* in_sizes, int n_in,
                              void* d_out, int out_size, void* d_ws, size_t ws_size,
                              hipStream_t stream) {
    const float* X = (const float*)d_in[0];
    const float* Y = (const float*)d_in[1];
    double* acc = (double*)d_ws;
    float* out = (float*)d_out;

    // Exact pytorch_msssim Gaussian window, computed in double on host.
    GW gw;
    double c[WIN], s = 0.0;
    for (int i = 0; i < WIN; ++i) {
        double d = (double)i - (double)(WIN / 2);
        c[i] = exp(-(d * d) / (2.0 * 1.5 * 1.5));
        s += c[i];
    }
    for (int i = 0; i < WIN; ++i) gw.w[i] = (float)(c[i] / s);

    ssim_zero<<<1, 64, 0, stream>>>(acc);
    dim3 grid(IMG / OW, IMG / OH, NIMG);   // (8, 16, 64)
    ssim_kernel<<<grid, 256, 0, stream>>>(X, Y, acc, gw);
    ssim_finalize<<<1, 1, 0, stream>>>(acc, out);
}